// Round 1
// baseline (157.438 us; speedup 1.0000x reference)
//
#include <hip/hip_runtime.h>
#include <hip/hip_bf16.h>

// Problem: anchor-box loss. B=8 batches, A=65536 anchors, G=32 gt boxes.
// Inputs (fp32 unless noted):
//   d_in[0] batch_boxes   (B,A,4)
//   d_in[1] batch_classes (B,A,2)
//   d_in[2] anchors       (A,4)  already xyxy
//   d_in[3] batch_gt      (B,G,4) xywh
//   d_in[4] batch_num_objects (B,) int32
// Output: 3 fp32 scalars: total_loss, class_loss, coord_loss

constexpr int B = 8;
constexpr int A = 65536;
constexpr int G = 32;
constexpr float THRESH = 0.5f;

// ---------------- workspace layout ----------------
// [0, 2048)         : unsigned long long best_packed[B*G]
// [2048, 2052)      : float class_total
// [2064, 2096)      : float coord_sum[B]
// [2096, 2128)      : unsigned int counts[B]
static constexpr size_t WS_BEST   = 0;
static constexpr size_t WS_CLASS  = 2048;
static constexpr size_t WS_COORD  = 2064;
static constexpr size_t WS_COUNT  = 2096;
static constexpr size_t WS_ZERO_BYTES = 2128;

__device__ __forceinline__ unsigned long long umax64(unsigned long long a, unsigned long long b) {
    return a > b ? a : b;
}

// Pass 1: per (b,g) argmax over anchors of IoU, first-index tie-break.
// grid (A/256, B), block 256. Thread layout: g = tid&31, sub = tid>>5,
// each thread scans 32 consecutive anchors.
__global__ __launch_bounds__(256) void argmax_kernel(
        const float* __restrict__ anchors,
        const float* __restrict__ gt,        // (B,G,4) xywh
        unsigned long long* __restrict__ best) {
    const int b   = blockIdx.y;
    const int tid = threadIdx.x;
    const int g   = tid & 31;
    const int sub = tid >> 5;

    // gt box -> xyxy (same fp32 ops as reference)
    const float4 q = ((const float4*)gt)[b * G + g];
    const float gx1 = q.x - q.z * 0.5f;
    const float gy1 = q.y - q.w * 0.5f;
    const float gx2 = q.x + q.z * 0.5f;
    const float gy2 = q.y + q.w * 0.5f;
    const float area_g = (gx2 - gx1) * (gy2 - gy1);

    const int a0 = blockIdx.x * 256 + sub * 32;
    unsigned long long bestp = 0ull;
    #pragma unroll 4
    for (int i = 0; i < 32; ++i) {
        const int a = a0 + i;
        const float4 an = ((const float4*)anchors)[a];
        const float area_a = (an.z - an.x) * (an.w - an.y);
        const float ltx = fmaxf(an.x, gx1);
        const float lty = fmaxf(an.y, gy1);
        const float rbx = fminf(an.z, gx2);
        const float rby = fminf(an.w, gy2);
        const float w = fmaxf(rbx - ltx, 0.0f);
        const float h = fmaxf(rby - lty, 0.0f);
        const float inter = w * h;
        const float iou = inter / (area_a + area_g - inter);
        // iou >= 0 always -> uint bit pattern is order-preserving.
        // Lower word 0xFFFFFFFF - a: at equal iou, larger packed = smaller
        // index, matching jnp.argmax first-occurrence semantics.
        const unsigned long long p =
            ((unsigned long long)__float_as_uint(iou) << 32) |
            (unsigned long long)(0xFFFFFFFFu - (unsigned int)a);
        bestp = umax64(bestp, p);
    }

    // Reduce the 8 sub-threads that share one g.
    // lanes l and l^32 share g: one xor-shuffle folds each wave to 32 values.
    bestp = umax64(bestp, (unsigned long long)__shfl_xor((unsigned long long)bestp, 32));
    __shared__ unsigned long long red[4 * 32];
    const int wave = tid >> 6;
    const int lane = tid & 63;
    if (lane < 32) red[wave * 32 + lane] = bestp;
    __syncthreads();
    if (tid < 32) {
        unsigned long long m = umax64(umax64(red[tid], red[32 + tid]),
                                      umax64(red[64 + tid], red[96 + tid]));
        atomicMax(&best[b * G + tid], m);
    }
}

// Pass 2: per-anchor pos mask, focal class term, coord diff sums.
// grid (A/256, B), block 256.
__global__ __launch_bounds__(256) void main_kernel(
        const float* __restrict__ boxes,     // (B,A,4)
        const float* __restrict__ classes,   // (B,A,2)
        const float* __restrict__ anchors,   // (A,4)
        const float* __restrict__ gt,        // (B,G,4) xywh
        const int* __restrict__ nobj,        // (B,)
        const unsigned long long* __restrict__ best,
        float* __restrict__ class_total,
        float* __restrict__ coord_sum,
        unsigned int* __restrict__ counts) {
    const int b   = blockIdx.y;
    const int tid = threadIdx.x;
    const int a   = blockIdx.x * 256 + tid;

    __shared__ float4 sgt[G];        // xyxy
    __shared__ float  sarea[G];
    __shared__ unsigned int sbest[G];
    if (tid < G) {
        const float4 q = ((const float4*)gt)[b * G + tid];
        const float gx1 = q.x - q.z * 0.5f;
        const float gy1 = q.y - q.w * 0.5f;
        const float gx2 = q.x + q.z * 0.5f;
        const float gy2 = q.y + q.w * 0.5f;
        sgt[tid] = make_float4(gx1, gy1, gx2, gy2);
        sarea[tid] = (gx2 - gx1) * (gy2 - gy1);
        sbest[tid] = 0xFFFFFFFFu - (unsigned int)(best[b * G + tid] & 0xFFFFFFFFull);
    }
    __syncthreads();

    const int n = nobj[b];
    const float4 an = ((const float4*)anchors)[a];
    const float area_a = (an.z - an.x) * (an.w - an.y);
    const float4 bx = ((const float4*)boxes)[(size_t)b * A + a];

    bool anchor_pos = false;
    float csum = 0.0f;
    unsigned int cnt = 0;
    for (int g = 0; g < n; ++g) {
        const float4 gb = sgt[g];
        const float ltx = fmaxf(an.x, gb.x);
        const float lty = fmaxf(an.y, gb.y);
        const float rbx = fminf(an.z, gb.z);
        const float rby = fminf(an.w, gb.w);
        const float w = fmaxf(rbx - ltx, 0.0f);
        const float h = fmaxf(rby - lty, 0.0f);
        const float inter = w * h;
        const float iou = inter / (area_a + sarea[g] - inter);
        const bool pos = (iou > THRESH) | (sbest[g] == (unsigned int)a);
        if (pos) {
            anchor_pos = true;
            cnt++;
            csum += fabsf(bx.x - gb.x) + fabsf(bx.y - gb.y) +
                    fabsf(bx.z - gb.z) + fabsf(bx.w - gb.w);
        }
    }

    const float2 cl = ((const float2*)classes)[(size_t)b * A + a];
    const float p = anchor_pos ? cl.y : cl.x;
    const float om = 1.0f - p;
    float cterm = -om * om * __logf(p);
    // use precise logf instead if needed; p in (0.001, 0.999)
    cterm = -om * om * logf(p);

    // block reduce csum, cterm, cnt
    float cs = csum, ct = cterm;
    unsigned int cc = cnt;
    #pragma unroll
    for (int off = 32; off > 0; off >>= 1) {
        cs += __shfl_down(cs, off);
        ct += __shfl_down(ct, off);
        cc += __shfl_down(cc, off);
    }
    __shared__ float s_cs[4], s_ct[4];
    __shared__ unsigned int s_cc[4];
    const int wave = tid >> 6;
    const int lane = tid & 63;
    if (lane == 0) { s_cs[wave] = cs; s_ct[wave] = ct; s_cc[wave] = cc; }
    __syncthreads();
    if (tid == 0) {
        const float bcs = s_cs[0] + s_cs[1] + s_cs[2] + s_cs[3];
        const float bct = s_ct[0] + s_ct[1] + s_ct[2] + s_ct[3];
        const unsigned int bcc = s_cc[0] + s_cc[1] + s_cc[2] + s_cc[3];
        atomicAdd(class_total, bct);
        atomicAdd(&coord_sum[b], bcs);
        atomicAdd(&counts[b], bcc);
    }
}

// Pass 3: finalize
__global__ void finalize_kernel(const float* __restrict__ class_total,
                                const float* __restrict__ coord_sum,
                                const unsigned int* __restrict__ counts,
                                float* __restrict__ out) {
    if (threadIdx.x == 0) {
        const float cl = (*class_total * 0.01f) / 8.0f;
        float co = 0.0f;
        for (int b = 0; b < B; ++b)
            co += coord_sum[b] / (4.0f * (float)counts[b]);
        co = co / 8.0f;
        out[0] = cl + co;
        out[1] = cl;
        out[2] = co;
    }
}

extern "C" void kernel_launch(void* const* d_in, const int* in_sizes, int n_in,
                              void* d_out, int out_size, void* d_ws, size_t ws_size,
                              hipStream_t stream) {
    const float* boxes   = (const float*)d_in[0];
    const float* classes = (const float*)d_in[1];
    const float* anchors = (const float*)d_in[2];
    const float* gt      = (const float*)d_in[3];
    const int*   nobj    = (const int*)d_in[4];
    float* out = (float*)d_out;

    unsigned long long* best = (unsigned long long*)((char*)d_ws + WS_BEST);
    float* class_total       = (float*)((char*)d_ws + WS_CLASS);
    float* coord_sum         = (float*)((char*)d_ws + WS_COORD);
    unsigned int* counts     = (unsigned int*)((char*)d_ws + WS_COUNT);

    // zero the accumulators (ws is re-poisoned to 0xAA before every call)
    hipMemsetAsync(d_ws, 0, WS_ZERO_BYTES, stream);

    dim3 grid(A / 256, B);
    argmax_kernel<<<grid, 256, 0, stream>>>(anchors, gt, best);
    main_kernel<<<grid, 256, 0, stream>>>(boxes, classes, anchors, gt, nobj,
                                          best, class_total, coord_sum, counts);
    finalize_kernel<<<1, 64, 0, stream>>>(class_total, coord_sum, counts, out);
}

// Round 2
// 101.089 us; speedup vs baseline: 1.5574x; 1.5574x over previous
//
#include <hip/hip_runtime.h>

// Anchor-box loss. B=8, A=65536 anchors, G=32 gt boxes, fp32.
// d_in[0] batch_boxes (B,A,4) | d_in[1] batch_classes (B,A,2)
// d_in[2] anchors (A,4) xyxy  | d_in[3] batch_gt (B,G,4) xywh
// d_in[4] batch_num_objects (B,) int32
// out: 3 fp32: total, class, coord
//
// Structure (no contended atomics, no memset, 4 launches):
//  K1 iou_kernel:    per (b, 256-anchor block): argmax partials (per-g best
//                    packed key) + per-anchor thresh posmask (division-free).
//  K2 argmax_final:  reduce 256 partials per (b,g); scatter forced bits into
//                    posmask (256 uncontended atomicOr).
//  K3 loss_kernel:   streaming pass: focal term always; coord diffs only
//                    where posmask != 0. Block partials to ws.
//  K4 finalize:      reduce 2048 partials -> 3 scalars.

constexpr int B = 8;
constexpr int A = 65536;
constexpr int G = 32;

// ---------------- workspace layout (~2.6 MB) ----------------
static constexpr size_t WS_PART = 0;                            // u64[2048*32] = 512 KB
static constexpr size_t WS_MASK = 512 * 1024;                   // u32[B*A]     = 2 MB
static constexpr size_t WS_CT   = WS_MASK + (size_t)B * A * 4;  // f32[2048]
static constexpr size_t WS_CO   = WS_CT + 2048 * 4;             // f32[2048]
static constexpr size_t WS_CN   = WS_CO + 2048 * 4;             // u32[2048]

__device__ __forceinline__ float fast_rcp(float x) {
#if __has_builtin(__builtin_amdgcn_rcpf)
    return __builtin_amdgcn_rcpf(x);   // v_rcp_f32: ordering-quality is plenty
#else
    return 1.0f / x;
#endif
}

__device__ __forceinline__ unsigned long long umax64(unsigned long long a, unsigned long long b) {
    return a > b ? a : b;
}

// K1: grid (A/256, B), block 256.
// Phase A: g = tid&31, sub = tid>>5; each thread scans 32 anchors for its g,
//          packing (iou_bits<<32)|(~a) so max == (max iou, then smallest a)
//          = jnp.argmax first-index semantics (iou >= 0 so uint order works).
// Phase B: a = base+tid; per-anchor mask bit g = (iou>0.5) for g<n, via
//          inter/U > 0.5  <=>  3*inter > area_a + area_g  (U>0 always).
__global__ __launch_bounds__(256) void iou_kernel(
        const float* __restrict__ anchors,
        const float* __restrict__ gt,        // (B,G,4) xywh
        const int* __restrict__ nobj,
        unsigned long long* __restrict__ part,
        unsigned int* __restrict__ posmask) {
    const int b   = blockIdx.y;
    const int bx  = blockIdx.x;
    const int tid = threadIdx.x;

    __shared__ float4 sgt[G];   // xyxy
    __shared__ float  sarea[G];
    if (tid < G) {
        const float4 q = ((const float4*)gt)[b * G + tid];
        const float x1 = q.x - q.z * 0.5f, y1 = q.y - q.w * 0.5f;
        const float x2 = q.x + q.z * 0.5f, y2 = q.y + q.w * 0.5f;
        sgt[tid]   = make_float4(x1, y1, x2, y2);
        sarea[tid] = (x2 - x1) * (y2 - y1);
    }
    __syncthreads();

    const int base = bx * 256;

    // ---- Phase A: per-g argmax over this block's 256 anchors ----
    const int g   = tid & 31;
    const int sub = tid >> 5;
    const float4 gb = sgt[g];
    const float  ag = sarea[g];
    const int a0 = base + sub * 32;
    unsigned long long bestp = 0ull;
    #pragma unroll 8
    for (int i = 0; i < 32; ++i) {
        const int a = a0 + i;
        const float4 an = ((const float4*)anchors)[a];
        const float area_a = (an.z - an.x) * (an.w - an.y);
        const float w = fmaxf(fminf(an.z, gb.z) - fmaxf(an.x, gb.x), 0.0f);
        const float h = fmaxf(fminf(an.w, gb.w) - fmaxf(an.y, gb.y), 0.0f);
        const float inter = w * h;
        const float iou = inter * fast_rcp(area_a + ag - inter);
        const unsigned long long p =
            ((unsigned long long)__float_as_uint(iou) << 32) |
            (unsigned long long)(0xFFFFFFFFu - (unsigned int)a);
        bestp = umax64(bestp, p);
    }
    bestp = umax64(bestp, (unsigned long long)__shfl_xor((unsigned long long)bestp, 32));
    __shared__ unsigned long long red[4 * 32];
    {
        const int wave = tid >> 6, lane = tid & 63;
        if (lane < 32) red[wave * 32 + lane] = bestp;
    }

    // ---- Phase B: per-anchor threshold mask (no divide) ----
    const int a = base + tid;
    const float4 an = ((const float4*)anchors)[a];
    const float area_a = (an.z - an.x) * (an.w - an.y);
    const int n = nobj[b];
    const unsigned int vm = (n >= 32) ? 0xFFFFFFFFu : ((1u << n) - 1u);
    unsigned int m = 0u;
    #pragma unroll 8
    for (int j = 0; j < G; ++j) {
        const float4 gj = sgt[j];
        const float w = fmaxf(fminf(an.z, gj.z) - fmaxf(an.x, gj.x), 0.0f);
        const float h = fmaxf(fminf(an.w, gj.w) - fmaxf(an.y, gj.y), 0.0f);
        const float inter = w * h;
        if (3.0f * inter > area_a + sarea[j]) m |= (1u << j);
    }
    posmask[b * A + a] = m & vm;

    __syncthreads();
    if (tid < 32) {
        const unsigned long long mm =
            umax64(umax64(red[tid], red[32 + tid]),
                   umax64(red[64 + tid], red[96 + tid]));
        part[((size_t)(b * 256 + bx)) * 32 + tid] = mm;
    }
}

// K2: grid (B), block 256. Reduce 256 block-partials per (b,g); scatter the
// forced bit for valid g into posmask (<=256 atomicOr, essentially uncontended).
__global__ __launch_bounds__(256) void argmax_final(
        const unsigned long long* __restrict__ part,
        const int* __restrict__ nobj,
        unsigned int* __restrict__ posmask) {
    const int b   = blockIdx.x;
    const int tid = threadIdx.x;
    const int g     = tid & 31;
    const int chunk = tid >> 5;

    unsigned long long m = 0ull;
    #pragma unroll 8
    for (int j = 0; j < 32; ++j) {
        const unsigned long long v =
            part[((size_t)(b * 256 + chunk * 32 + j)) * 32 + g];
        m = umax64(m, v);
    }
    __shared__ unsigned long long red[256];
    red[tid] = m;
    __syncthreads();
    if (tid < 32) {
        unsigned long long mm = red[tid];
        #pragma unroll
        for (int c = 1; c < 8; ++c) mm = umax64(mm, red[c * 32 + tid]);
        if (tid < nobj[b]) {
            const unsigned int abest = 0xFFFFFFFFu - (unsigned int)(mm & 0xFFFFFFFFull);
            atomicOr(&posmask[b * A + abest], 1u << tid);
        }
    }
}

// K3: grid (A/256, B), block 256. Streaming focal + sparse coord sums.
__global__ __launch_bounds__(256) void loss_kernel(
        const float* __restrict__ boxes,     // (B,A,4)
        const float* __restrict__ classes,   // (B,A,2)
        const float* __restrict__ gt,        // (B,G,4) xywh
        const unsigned int* __restrict__ posmask,
        float* __restrict__ ct_p,
        float* __restrict__ co_p,
        unsigned int* __restrict__ cn_p) {
    const int b   = blockIdx.y;
    const int bx  = blockIdx.x;
    const int tid = threadIdx.x;

    __shared__ float4 sgt[G];   // xyxy
    if (tid < G) {
        const float4 q = ((const float4*)gt)[b * G + tid];
        sgt[tid] = make_float4(q.x - q.z * 0.5f, q.y - q.w * 0.5f,
                               q.x + q.z * 0.5f, q.y + q.w * 0.5f);
    }
    __syncthreads();

    const int a = bx * 256 + tid;
    unsigned int m = posmask[b * A + a];
    const float2 cl = ((const float2*)classes)[(size_t)b * A + a];
    const float p  = m ? cl.y : cl.x;
    const float om = 1.0f - p;
    float ct = -om * om * __logf(p);   // p in (0.001, 0.999): fast log is safe

    float cs = 0.0f;
    unsigned int cn = 0;
    if (m) {
        const float4 bx4 = ((const float4*)boxes)[(size_t)b * A + a];
        cn = (unsigned int)__popc(m);
        do {
            const int j = __ffs(m) - 1;
            m &= m - 1;
            const float4 gj = sgt[j];
            cs += fabsf(bx4.x - gj.x) + fabsf(bx4.y - gj.y) +
                  fabsf(bx4.z - gj.z) + fabsf(bx4.w - gj.w);
        } while (m);
    }

    #pragma unroll
    for (int off = 32; off > 0; off >>= 1) {
        ct += __shfl_down(ct, off);
        cs += __shfl_down(cs, off);
        cn += __shfl_down(cn, off);
    }
    __shared__ float s_ct[4], s_cs[4];
    __shared__ unsigned int s_cn[4];
    const int wave = tid >> 6, lane = tid & 63;
    if (lane == 0) { s_ct[wave] = ct; s_cs[wave] = cs; s_cn[wave] = cn; }
    __syncthreads();
    if (tid == 0) {
        ct_p[b * 256 + bx] = s_ct[0] + s_ct[1] + s_ct[2] + s_ct[3];
        co_p[b * 256 + bx] = s_cs[0] + s_cs[1] + s_cs[2] + s_cs[3];
        cn_p[b * 256 + bx] = s_cn[0] + s_cn[1] + s_cn[2] + s_cn[3];
    }
}

// K4: one block of 256, reduce 2048 partials -> 3 scalars.
__global__ __launch_bounds__(256) void finalize_kernel(
        const float* __restrict__ ct_p,
        const float* __restrict__ co_p,
        const unsigned int* __restrict__ cn_p,
        float* __restrict__ out) {
    const int tid = threadIdx.x;
    const int wave = tid >> 6, lane = tid & 63;
    __shared__ float sa[4], sb[4];

    // class total
    float v = 0.0f;
    #pragma unroll
    for (int i = 0; i < 8; ++i) v += ct_p[i * 256 + tid];
    #pragma unroll
    for (int off = 32; off > 0; off >>= 1) v += __shfl_down(v, off);
    if (lane == 0) sa[wave] = v;
    __syncthreads();
    const float cls = (sa[0] + sa[1] + sa[2] + sa[3]) * (0.01f / 8.0f);

    float co = 0.0f;
    for (int b = 0; b < B; ++b) {
        float c = co_p[b * 256 + tid];
        float n = (float)cn_p[b * 256 + tid];
        #pragma unroll
        for (int off = 32; off > 0; off >>= 1) {
            c += __shfl_down(c, off);
            n += __shfl_down(n, off);
        }
        __syncthreads();            // protect sa/sb reuse from previous iter
        if (lane == 0) { sa[wave] = c; sb[wave] = n; }
        __syncthreads();
        co += (sa[0] + sa[1] + sa[2] + sa[3]) /
              (4.0f * (sb[0] + sb[1] + sb[2] + sb[3]));
    }
    if (tid == 0) {
        co *= (1.0f / 8.0f);
        out[0] = cls + co;
        out[1] = cls;
        out[2] = co;
    }
}

extern "C" void kernel_launch(void* const* d_in, const int* in_sizes, int n_in,
                              void* d_out, int out_size, void* d_ws, size_t ws_size,
                              hipStream_t stream) {
    const float* boxes   = (const float*)d_in[0];
    const float* classes = (const float*)d_in[1];
    const float* anchors = (const float*)d_in[2];
    const float* gt      = (const float*)d_in[3];
    const int*   nobj    = (const int*)d_in[4];
    float* out = (float*)d_out;

    unsigned long long* part = (unsigned long long*)((char*)d_ws + WS_PART);
    unsigned int* posmask    = (unsigned int*)((char*)d_ws + WS_MASK);
    float* ct_p              = (float*)((char*)d_ws + WS_CT);
    float* co_p              = (float*)((char*)d_ws + WS_CO);
    unsigned int* cn_p       = (unsigned int*)((char*)d_ws + WS_CN);

    dim3 grid(A / 256, B);
    iou_kernel<<<grid, 256, 0, stream>>>(anchors, gt, nobj, part, posmask);
    argmax_final<<<dim3(B), 256, 0, stream>>>(part, nobj, posmask);
    loss_kernel<<<grid, 256, 0, stream>>>(boxes, classes, gt, posmask,
                                          ct_p, co_p, cn_p);
    finalize_kernel<<<1, 256, 0, stream>>>(ct_p, co_p, cn_p, out);
}

// Round 3
// 92.154 us; speedup vs baseline: 1.7084x; 1.0970x over previous
//
#include <hip/hip_runtime.h>

// Anchor-box loss. B=8, A=65536 anchors, G=32 gt boxes, fp32.
// d_in[0] batch_boxes (B,A,4) | d_in[1] batch_classes (B,A,2)
// d_in[2] anchors (A,4) xyxy  | d_in[3] batch_gt (B,G,4) xywh
// d_in[4] batch_num_objects (B,) int32
// out: 3 fp32: total, class, coord
//
// 3 launches, each IoU computed exactly once, no posmask array, no contended
// atomics:
//  K1 fused_kernel: per (b, 256-anchor block): IoUs once; __ballot turns the
//     per-(a,g) threshold predicates into per-anchor masks; focal class term
//     + sparse coord sums inline; argmax partials per (b,g).
//  K2 correct_kernel: reduce argmax partials -> best anchor per (b,g);
//     recompute that anchor's thresh mask (32 IoUs); emit scalar corrections
//     (forced coord pairs + class flips, duplicate-anchor de-dup).
//  K3 finalize: reduce 2048 block partials + corrections -> 3 scalars.

constexpr int B = 8;
constexpr int A = 65536;
constexpr int G = 32;

// ---------------- workspace layout ----------------
static constexpr size_t WS_PART    = 0;                      // u64[2048*32] = 512 KB
static constexpr size_t WS_CT      = 512 * 1024;             // f32[2048]
static constexpr size_t WS_CO      = WS_CT + 2048 * 4;       // f32[2048]
static constexpr size_t WS_CN      = WS_CO + 2048 * 4;       // u32[2048]
static constexpr size_t WS_CORR_CT = WS_CN + 2048 * 4;       // f32[8]
static constexpr size_t WS_CORR_CO = WS_CORR_CT + 32;        // f32[8]
static constexpr size_t WS_CORR_CN = WS_CORR_CO + 32;        // u32[8]

__device__ __forceinline__ float fast_rcp(float x) {
#if __has_builtin(__builtin_amdgcn_rcpf)
    return __builtin_amdgcn_rcpf(x);
#else
    return 1.0f / x;
#endif
}

__device__ __forceinline__ unsigned long long umax64(unsigned long long a, unsigned long long b) {
    return a > b ? a : b;
}

// K1: grid (A/256, B), block 256 (4 waves). Wave w owns anchors
// [base+w*64, base+w*64+64). Lane = (g, half): loops i=0..31 computing
// iou(anchor = chunk + half*32 + i, g).
//  - argmax partial: packed (iou_bits<<32)|(~a) so u64-max == (max iou,
//    smallest index) = jnp.argmax first-occurrence. iou >= 0 so uint order ok.
//  - thresh mask: iou > 0.5 <=> 3*inter > area_a + area_g (union > 0).
//    __ballot: low 32 bits = mask of anchor chunk+i, high 32 = chunk+32+i.
//    Lane i keeps the low word, lane 32+i the high word -> after the loop,
//    lane l holds the mask of anchor chunk+l.
__global__ __launch_bounds__(256) void fused_kernel(
        const float* __restrict__ boxes,     // (B,A,4)
        const float* __restrict__ classes,   // (B,A,2)
        const float* __restrict__ anchors,   // (A,4)
        const float* __restrict__ gt,        // (B,G,4) xywh
        const int* __restrict__ nobj,
        unsigned long long* __restrict__ part,
        float* __restrict__ ct_p,
        float* __restrict__ co_p,
        unsigned int* __restrict__ cn_p) {
    const int b    = blockIdx.y;
    const int bx   = blockIdx.x;
    const int tid  = threadIdx.x;
    const int base = bx * 256;

    __shared__ float4 sgt[G];
    __shared__ float  sarea[G];
    __shared__ float4 sA[256];
    __shared__ float  sAarea[256];
    if (tid < G) {
        const float4 q = ((const float4*)gt)[b * G + tid];
        const float x1 = q.x - q.z * 0.5f, y1 = q.y - q.w * 0.5f;
        const float x2 = q.x + q.z * 0.5f, y2 = q.y + q.w * 0.5f;
        sgt[tid]   = make_float4(x1, y1, x2, y2);
        sarea[tid] = (x2 - x1) * (y2 - y1);
    }
    {
        const float4 an = ((const float4*)anchors)[base + tid];
        sA[tid] = an;
        sAarea[tid] = (an.z - an.x) * (an.w - an.y);
    }
    __syncthreads();

    const int wave = tid >> 6;
    const int lane = tid & 63;
    const int g    = lane & 31;
    const int half = lane >> 5;
    const int chunk = wave * 64;

    const float4 gb = sgt[g];
    const float  ag = sarea[g];

    unsigned long long bestp = 0ull;
    unsigned int mymask = 0u;
    #pragma unroll 4
    for (int i = 0; i < 32; ++i) {
        const int idx = chunk + half * 32 + i;
        const float4 an = sA[idx];
        const float  aa = sAarea[idx];
        const float w = fmaxf(fminf(an.z, gb.z) - fmaxf(an.x, gb.x), 0.0f);
        const float h = fmaxf(fminf(an.w, gb.w) - fmaxf(an.y, gb.y), 0.0f);
        const float inter = w * h;
        const float iou = inter * fast_rcp(aa + ag - inter);
        const unsigned int a_glob = (unsigned int)(base + idx);
        const unsigned long long p =
            ((unsigned long long)__float_as_uint(iou) << 32) |
            (unsigned long long)(0xFFFFFFFFu - a_glob);
        bestp = umax64(bestp, p);

        const unsigned long long bal = __ballot(3.0f * inter > aa + ag);
        if (lane == i)      mymask = (unsigned int)bal;
        if (lane == 32 + i) mymask = (unsigned int)(bal >> 32);
    }

    // fold halves: lanes l, l^32 share g
    bestp = umax64(bestp, (unsigned long long)__shfl_xor((unsigned long long)bestp, 32));
    __shared__ unsigned long long red[4 * 32];
    if (lane < 32) red[wave * 32 + lane] = bestp;

    // ---- per-lane epilogue: lane owns anchor a = base + chunk + lane ----
    const int n = nobj[b];
    const unsigned int vm = (n >= 32) ? 0xFFFFFFFFu : ((1u << n) - 1u);
    unsigned int m = mymask & vm;
    const int a = base + chunk + lane;
    const float2 cl = ((const float2*)classes)[(size_t)b * A + a];
    const float p  = m ? cl.y : cl.x;
    const float om = 1.0f - p;
    float ct = -om * om * __logf(p);    // p in (0.001, 0.999)

    float cs = 0.0f;
    unsigned int cn = 0;
    if (m) {
        const float4 bx4 = ((const float4*)boxes)[(size_t)b * A + a];
        cn = (unsigned int)__popc(m);
        do {
            const int j = __ffs(m) - 1;
            m &= m - 1;
            const float4 gj = sgt[j];
            cs += fabsf(bx4.x - gj.x) + fabsf(bx4.y - gj.y) +
                  fabsf(bx4.z - gj.z) + fabsf(bx4.w - gj.w);
        } while (m);
    }

    #pragma unroll
    for (int off = 32; off > 0; off >>= 1) {
        ct += __shfl_down(ct, off);
        cs += __shfl_down(cs, off);
        cn += __shfl_down(cn, off);
    }
    __shared__ float s_ct[4], s_cs[4];
    __shared__ unsigned int s_cn[4];
    if (lane == 0) { s_ct[wave] = ct; s_cs[wave] = cs; s_cn[wave] = cn; }
    __syncthreads();
    if (tid == 0) {
        ct_p[b * 256 + bx] = s_ct[0] + s_ct[1] + s_ct[2] + s_ct[3];
        co_p[b * 256 + bx] = s_cs[0] + s_cs[1] + s_cs[2] + s_cs[3];
        cn_p[b * 256 + bx] = s_cn[0] + s_cn[1] + s_cn[2] + s_cn[3];
    }
    if (tid < 32) {
        const unsigned long long mm =
            umax64(umax64(red[tid], red[32 + tid]),
                   umax64(red[64 + tid], red[96 + tid]));
        part[((size_t)(b * 256 + bx)) * 32 + tid] = mm;
    }
}

// K2: grid (B), block 256. Reduce argmax partials; lanes 0-31 recompute the
// best anchor's thresh mask and emit corrections:
//  - coord: pair (abest[g], g) if thresh bit g not already set
//  - class: flip cl.x->cl.y focal term if anchor had empty thresh mask,
//    applied once per distinct anchor (smallest-g lane wins).
__global__ __launch_bounds__(256) void correct_kernel(
        const float* __restrict__ boxes,
        const float* __restrict__ classes,
        const float* __restrict__ anchors,
        const float* __restrict__ gt,
        const int* __restrict__ nobj,
        const unsigned long long* __restrict__ part,
        float* __restrict__ corr_ct,
        float* __restrict__ corr_co,
        unsigned int* __restrict__ corr_cn) {
    const int b   = blockIdx.x;
    const int tid = threadIdx.x;

    __shared__ float4 sgt[G];
    __shared__ float  sarea[G];
    if (tid < G) {
        const float4 q = ((const float4*)gt)[b * G + tid];
        const float x1 = q.x - q.z * 0.5f, y1 = q.y - q.w * 0.5f;
        const float x2 = q.x + q.z * 0.5f, y2 = q.y + q.w * 0.5f;
        sgt[tid]   = make_float4(x1, y1, x2, y2);
        sarea[tid] = (x2 - x1) * (y2 - y1);
    }

    // reduce 256 chunk-partials per g
    const int g     = tid & 31;
    const int chunk = tid >> 5;
    unsigned long long m = 0ull;
    #pragma unroll 8
    for (int j = 0; j < 32; ++j)
        m = umax64(m, part[((size_t)(b * 256 + chunk * 32 + j)) * 32 + g]);
    __shared__ unsigned long long red[256];
    red[tid] = m;
    __syncthreads();

    __shared__ unsigned int sbest[32];
    if (tid < 32) {
        unsigned long long mm = red[tid];
        #pragma unroll
        for (int c = 1; c < 8; ++c) mm = umax64(mm, red[c * 32 + tid]);
        sbest[tid] = 0xFFFFFFFFu - (unsigned int)(mm & 0xFFFFFFFFull);
    }
    __syncthreads();

    if (tid < 32) {
        const int n = nobj[b];
        const unsigned int vm = (n >= 32) ? 0xFFFFFFFFu : ((1u << n) - 1u);
        const bool valid = tid < n;
        const unsigned int abest = sbest[tid];

        // recompute thresh mask of anchor abest
        const float4 an = ((const float4*)anchors)[abest];
        const float aa = (an.z - an.x) * (an.w - an.y);
        unsigned int M = 0u;
        #pragma unroll 8
        for (int j = 0; j < G; ++j) {
            const float4 gj = sgt[j];
            const float w = fmaxf(fminf(an.z, gj.z) - fmaxf(an.x, gj.x), 0.0f);
            const float h = fmaxf(fminf(an.w, gj.w) - fmaxf(an.y, gj.y), 0.0f);
            const float inter = w * h;
            if (3.0f * inter > aa + sarea[j]) M |= (1u << j);
        }
        M &= vm;

        float co_c = 0.0f, ct_c = 0.0f;
        unsigned int cn_c = 0u;
        if (valid && !((M >> tid) & 1u)) {
            const float4 bx4 = ((const float4*)boxes)[(size_t)b * A + abest];
            const float4 gj = sgt[tid];
            co_c = fabsf(bx4.x - gj.x) + fabsf(bx4.y - gj.y) +
                   fabsf(bx4.z - gj.z) + fabsf(bx4.w - gj.w);
            cn_c = 1u;
        }
        // class flip once per distinct forced anchor with empty thresh mask
        bool dup = false;
        #pragma unroll
        for (int j = 0; j < 32; ++j) {
            const unsigned int aj = (unsigned int)__shfl((int)abest, j);
            if (j < tid && j < n && aj == abest) dup = true;
        }
        if (valid && M == 0u && !dup) {
            const float2 cl = ((const float2*)classes)[(size_t)b * A + abest];
            const float op = 1.0f - cl.y, on = 1.0f - cl.x;
            ct_c = (-op * op * __logf(cl.y)) - (-on * on * __logf(cl.x));
        }

        #pragma unroll
        for (int off = 16; off > 0; off >>= 1) {
            co_c += __shfl_down(co_c, off);
            ct_c += __shfl_down(ct_c, off);
            cn_c += __shfl_down(cn_c, off);
        }
        if (tid == 0) {
            corr_ct[b] = ct_c;
            corr_co[b] = co_c;
            corr_cn[b] = cn_c;
        }
    }
}

// K3: one block of 256, reduce 2048 partials + corrections -> 3 scalars.
__global__ __launch_bounds__(256) void finalize_kernel(
        const float* __restrict__ ct_p,
        const float* __restrict__ co_p,
        const unsigned int* __restrict__ cn_p,
        const float* __restrict__ corr_ct,
        const float* __restrict__ corr_co,
        const unsigned int* __restrict__ corr_cn,
        float* __restrict__ out) {
    const int tid = threadIdx.x;
    const int wave = tid >> 6, lane = tid & 63;
    __shared__ float sa[4], sb[4];

    float v = 0.0f;
    #pragma unroll
    for (int i = 0; i < 8; ++i) v += ct_p[i * 256 + tid];
    #pragma unroll
    for (int off = 32; off > 0; off >>= 1) v += __shfl_down(v, off);
    if (lane == 0) sa[wave] = v;
    __syncthreads();
    float ctot = sa[0] + sa[1] + sa[2] + sa[3];
    for (int b = 0; b < B; ++b) ctot += corr_ct[b];
    const float cls = ctot * (0.01f / 8.0f);

    float co = 0.0f;
    for (int b = 0; b < B; ++b) {
        float c = co_p[b * 256 + tid];
        float n = (float)cn_p[b * 256 + tid];
        #pragma unroll
        for (int off = 32; off > 0; off >>= 1) {
            c += __shfl_down(c, off);
            n += __shfl_down(n, off);
        }
        __syncthreads();
        if (lane == 0) { sa[wave] = c; sb[wave] = n; }
        __syncthreads();
        co += (sa[0] + sa[1] + sa[2] + sa[3] + corr_co[b]) /
              (4.0f * (sb[0] + sb[1] + sb[2] + sb[3] + (float)corr_cn[b]));
    }
    if (tid == 0) {
        co *= (1.0f / 8.0f);
        out[0] = cls + co;
        out[1] = cls;
        out[2] = co;
    }
}

extern "C" void kernel_launch(void* const* d_in, const int* in_sizes, int n_in,
                              void* d_out, int out_size, void* d_ws, size_t ws_size,
                              hipStream_t stream) {
    const float* boxes   = (const float*)d_in[0];
    const float* classes = (const float*)d_in[1];
    const float* anchors = (const float*)d_in[2];
    const float* gt      = (const float*)d_in[3];
    const int*   nobj    = (const int*)d_in[4];
    float* out = (float*)d_out;

    unsigned long long* part = (unsigned long long*)((char*)d_ws + WS_PART);
    float* ct_p        = (float*)((char*)d_ws + WS_CT);
    float* co_p        = (float*)((char*)d_ws + WS_CO);
    unsigned int* cn_p = (unsigned int*)((char*)d_ws + WS_CN);
    float* corr_ct     = (float*)((char*)d_ws + WS_CORR_CT);
    float* corr_co     = (float*)((char*)d_ws + WS_CORR_CO);
    unsigned int* corr_cn = (unsigned int*)((char*)d_ws + WS_CORR_CN);

    dim3 grid(A / 256, B);
    fused_kernel<<<grid, 256, 0, stream>>>(boxes, classes, anchors, gt, nobj,
                                           part, ct_p, co_p, cn_p);
    correct_kernel<<<dim3(B), 256, 0, stream>>>(boxes, classes, anchors, gt,
                                                nobj, part,
                                                corr_ct, corr_co, corr_cn);
    finalize_kernel<<<1, 256, 0, stream>>>(ct_p, co_p, cn_p,
                                           corr_ct, corr_co, corr_cn, out);
}

// Round 4
// 88.309 us; speedup vs baseline: 1.7828x; 1.0435x over previous
//
#include <hip/hip_runtime.h>

// Anchor-box loss. B=8, A=65536 anchors, G=32 gt boxes, fp32.
// d_in[0] batch_boxes (B,A,4) | d_in[1] batch_classes (B,A,2)
// d_in[2] anchors (A,4) xyxy  | d_in[3] batch_gt (B,G,4) xywh
// d_in[4] batch_num_objects (B,) int32
// out: 3 fp32: total, class, coord
//
// 3 launches, IoU computed once, no posmask array, no contended atomics:
//  K1 fused_kernel: per (b, 256-anchor block): IoUs once; running
//     (best_iou,best_i) per lane-g (packed to u64 key post-loop); __ballot
//     turns per-(a,g) iou>0.5 predicates into per-anchor masks; focal class
//     term + sparse coord sums inline; argmax partials per (b,g).
//  K2 correct_kernel: reduce argmax partials -> best anchor per (b,g);
//     recompute that anchor's 32 predicates (identical instruction sequence);
//     emit scalar corrections (forced pairs + class flips, de-duped); ALSO
//     reduce the 256 block partials for its batch -> 3 scalars per b.
//  K3 finalize: single wave, 24 scalar loads -> 3 outputs.

constexpr int B = 8;
constexpr int A = 65536;
constexpr int G = 32;

// ---------------- workspace layout ----------------
static constexpr size_t WS_PART = 0;                   // u64[2048*32] = 512 KB
static constexpr size_t WS_CT   = 512 * 1024;          // f32[2048]
static constexpr size_t WS_CO   = WS_CT + 2048 * 4;    // f32[2048]
static constexpr size_t WS_CN   = WS_CO + 2048 * 4;    // u32[2048]
static constexpr size_t WS_SCT  = WS_CN + 2048 * 4;    // f32[8]  per-b class sum (corr folded)
static constexpr size_t WS_SCO  = WS_SCT + 32;         // f32[8]  per-b coord sum (corr folded)
static constexpr size_t WS_SCN  = WS_SCO + 32;         // u32[8]  per-b pair count (corr folded)

__device__ __forceinline__ float fast_rcp(float x) {
#if __has_builtin(__builtin_amdgcn_rcpf)
    return __builtin_amdgcn_rcpf(x);
#else
    return 1.0f / x;
#endif
}

__device__ __forceinline__ unsigned long long umax64(unsigned long long a, unsigned long long b) {
    return a > b ? a : b;
}

// K1: grid (A/256, B), block 256 (4 waves). Wave w owns anchors
// [base+w*64, base+w*64+64). Lane = (g, half); iterates i=0..31 over
// anchor = chunk + half*32 + i (staged in LDS).
//  - argmax: running (best_iou, best_i); strict > keeps smallest i =
//    jnp.argmax first-occurrence within the lane's ascending scan. Packed
//    once post-loop as (iou_bits<<32)|(~a): u64-max == (max iou, min index).
//  - thresh mask via __ballot(iou > 0.5f): low 32 bits = anchor chunk+i,
//    high 32 = chunk+32+i, bit position = g. Lane l captures word for its
//    own anchor chunk+l over the 32 iterations.
__global__ __launch_bounds__(256) void fused_kernel(
        const float* __restrict__ boxes,     // (B,A,4)
        const float* __restrict__ classes,   // (B,A,2)
        const float* __restrict__ anchors,   // (A,4)
        const float* __restrict__ gt,        // (B,G,4) xywh
        const int* __restrict__ nobj,
        unsigned long long* __restrict__ part,
        float* __restrict__ ct_p,
        float* __restrict__ co_p,
        unsigned int* __restrict__ cn_p) {
    const int b    = blockIdx.y;
    const int bx   = blockIdx.x;
    const int tid  = threadIdx.x;
    const int base = bx * 256;

    __shared__ float4 sgt[G];
    __shared__ float  sarea[G];
    __shared__ float4 sA[256];
    __shared__ float  sAarea[256];
    if (tid < G) {
        const float4 q = ((const float4*)gt)[b * G + tid];
        const float x1 = q.x - q.z * 0.5f, y1 = q.y - q.w * 0.5f;
        const float x2 = q.x + q.z * 0.5f, y2 = q.y + q.w * 0.5f;
        sgt[tid]   = make_float4(x1, y1, x2, y2);
        sarea[tid] = (x2 - x1) * (y2 - y1);
    }
    {
        const float4 an = ((const float4*)anchors)[base + tid];
        sA[tid] = an;
        sAarea[tid] = (an.z - an.x) * (an.w - an.y);
    }
    __syncthreads();

    const int wave  = tid >> 6;
    const int lane  = tid & 63;
    const int g     = lane & 31;
    const int half  = lane >> 5;
    const int chunk = wave * 64;

    const float4 gb = sgt[g];
    const float  ag = sarea[g];

    float best_iou = -1.0f;
    int   best_i   = 0;
    unsigned int mymask = 0u;
    #pragma unroll 4
    for (int i = 0; i < 32; ++i) {
        const int idx = chunk + half * 32 + i;
        const float4 an = sA[idx];
        const float  aa = sAarea[idx];
        const float w = fmaxf(fminf(an.z, gb.z) - fmaxf(an.x, gb.x), 0.0f);
        const float h = fmaxf(fminf(an.w, gb.w) - fmaxf(an.y, gb.y), 0.0f);
        const float inter = w * h;
        const float U   = aa + ag - inter;      // > 0 always
        const float iou = inter * fast_rcp(U);
        if (iou > best_iou) { best_iou = iou; best_i = i; }
        const unsigned long long bal = __ballot(iou > 0.5f);
        if (lane == i)      mymask = (unsigned int)bal;
        if (lane == 32 + i) mymask = (unsigned int)(bal >> 32);
    }
    const unsigned int a_best = (unsigned int)(base + chunk + half * 32 + best_i);
    unsigned long long bestp =
        ((unsigned long long)__float_as_uint(best_iou) << 32) |
        (unsigned long long)(0xFFFFFFFFu - a_best);

    // fold halves: lanes l, l^32 share g
    bestp = umax64(bestp, (unsigned long long)__shfl_xor((unsigned long long)bestp, 32));
    __shared__ unsigned long long red[4 * 32];
    if (lane < 32) red[wave * 32 + lane] = bestp;

    // ---- per-lane epilogue: lane owns anchor a = base + chunk + lane ----
    const int n = nobj[b];
    const unsigned int vm = (n >= 32) ? 0xFFFFFFFFu : ((1u << n) - 1u);
    unsigned int m = mymask & vm;
    const int a = base + chunk + lane;
    const float2 cl = ((const float2*)classes)[(size_t)b * A + a];
    const float p  = m ? cl.y : cl.x;
    const float om = 1.0f - p;
    float ct = -om * om * __logf(p);    // p in (0.001, 0.999)

    float cs = 0.0f;
    unsigned int cn = 0;
    if (m) {
        const float4 bx4 = ((const float4*)boxes)[(size_t)b * A + a];
        cn = (unsigned int)__popc(m);
        do {
            const int j = __ffs(m) - 1;
            m &= m - 1;
            const float4 gj = sgt[j];
            cs += fabsf(bx4.x - gj.x) + fabsf(bx4.y - gj.y) +
                  fabsf(bx4.z - gj.z) + fabsf(bx4.w - gj.w);
        } while (m);
    }

    #pragma unroll
    for (int off = 32; off > 0; off >>= 1) {
        ct += __shfl_down(ct, off);
        cs += __shfl_down(cs, off);
        cn += __shfl_down(cn, off);
    }
    __shared__ float s_ct[4], s_cs[4];
    __shared__ unsigned int s_cn[4];
    if (lane == 0) { s_ct[wave] = ct; s_cs[wave] = cs; s_cn[wave] = cn; }
    __syncthreads();
    if (tid == 0) {
        ct_p[b * 256 + bx] = s_ct[0] + s_ct[1] + s_ct[2] + s_ct[3];
        co_p[b * 256 + bx] = s_cs[0] + s_cs[1] + s_cs[2] + s_cs[3];
        cn_p[b * 256 + bx] = s_cn[0] + s_cn[1] + s_cn[2] + s_cn[3];
    }
    if (tid < 32) {
        const unsigned long long mm =
            umax64(umax64(red[tid], red[32 + tid]),
                   umax64(red[64 + tid], red[96 + tid]));
        part[((size_t)(b * 256 + bx)) * 32 + tid] = mm;
    }
}

// K2: grid (B), block 256. Reduce argmax partials -> best anchor per (b,g);
// lanes 0-31 recompute that anchor's predicates (same instruction sequence as
// K1) and emit corrections; then the whole block reduces its batch's 256
// partials and writes 3 per-b scalars with corrections folded in.
__global__ __launch_bounds__(256) void correct_kernel(
        const float* __restrict__ boxes,
        const float* __restrict__ classes,
        const float* __restrict__ anchors,
        const float* __restrict__ gt,
        const int* __restrict__ nobj,
        const unsigned long long* __restrict__ part,
        const float* __restrict__ ct_p,
        const float* __restrict__ co_p,
        const unsigned int* __restrict__ cn_p,
        float* __restrict__ S_ct,
        float* __restrict__ S_co,
        unsigned int* __restrict__ S_cn) {
    const int b   = blockIdx.x;
    const int tid = threadIdx.x;

    __shared__ float4 sgt[G];
    __shared__ float  sarea[G];
    if (tid < G) {
        const float4 q = ((const float4*)gt)[b * G + tid];
        const float x1 = q.x - q.z * 0.5f, y1 = q.y - q.w * 0.5f;
        const float x2 = q.x + q.z * 0.5f, y2 = q.y + q.w * 0.5f;
        sgt[tid]   = make_float4(x1, y1, x2, y2);
        sarea[tid] = (x2 - x1) * (y2 - y1);
    }

    // reduce 256 chunk-partials per g (coalesced: consecutive tid -> consecutive g)
    const int g     = tid & 31;
    const int chunk = tid >> 5;
    unsigned long long m = 0ull;
    #pragma unroll 8
    for (int j = 0; j < 32; ++j)
        m = umax64(m, part[((size_t)(b * 256 + chunk * 32 + j)) * 32 + g]);
    __shared__ unsigned long long red[256];
    red[tid] = m;
    __syncthreads();

    __shared__ unsigned int sbest[32];
    if (tid < 32) {
        unsigned long long mm = red[tid];
        #pragma unroll
        for (int c = 1; c < 8; ++c) mm = umax64(mm, red[c * 32 + tid]);
        sbest[tid] = 0xFFFFFFFFu - (unsigned int)(mm & 0xFFFFFFFFull);
    }
    __syncthreads();

    __shared__ float sh_ct_c, sh_co_c;
    __shared__ unsigned int sh_cn_c;
    if (tid < 32) {
        const int n = nobj[b];
        const unsigned int vm = (n >= 32) ? 0xFFFFFFFFu : ((1u << n) - 1u);
        const bool valid = tid < n;
        const unsigned int abest = sbest[tid];

        // recompute the best anchor's thresh mask — identical predicate to K1
        const float4 an = ((const float4*)anchors)[abest];
        const float aa = (an.z - an.x) * (an.w - an.y);
        unsigned int M = 0u;
        #pragma unroll 8
        for (int j = 0; j < G; ++j) {
            const float4 gj = sgt[j];
            const float w = fmaxf(fminf(an.z, gj.z) - fmaxf(an.x, gj.x), 0.0f);
            const float h = fmaxf(fminf(an.w, gj.w) - fmaxf(an.y, gj.y), 0.0f);
            const float inter = w * h;
            const float U = aa + sarea[j] - inter;
            if (inter * fast_rcp(U) > 0.5f) M |= (1u << j);
        }
        M &= vm;

        float co_c = 0.0f, ct_c = 0.0f;
        unsigned int cn_c = 0u;
        if (valid && !((M >> tid) & 1u)) {
            const float4 bx4 = ((const float4*)boxes)[(size_t)b * A + abest];
            const float4 gj = sgt[tid];
            co_c = fabsf(bx4.x - gj.x) + fabsf(bx4.y - gj.y) +
                   fabsf(bx4.z - gj.z) + fabsf(bx4.w - gj.w);
            cn_c = 1u;
        }
        // class flip once per distinct forced anchor with empty thresh mask
        bool dup = false;
        #pragma unroll
        for (int j = 0; j < 32; ++j) {
            const unsigned int aj = (unsigned int)__shfl((int)abest, j);
            if (j < tid && j < n && aj == abest) dup = true;
        }
        if (valid && M == 0u && !dup) {
            const float2 cl = ((const float2*)classes)[(size_t)b * A + abest];
            const float op = 1.0f - cl.y, on = 1.0f - cl.x;
            ct_c = (-op * op * __logf(cl.y)) - (-on * on * __logf(cl.x));
        }

        #pragma unroll
        for (int off = 16; off > 0; off >>= 1) {
            co_c += __shfl_down(co_c, off);
            ct_c += __shfl_down(ct_c, off);
            cn_c += __shfl_down(cn_c, off);
        }
        if (tid == 0) { sh_ct_c = ct_c; sh_co_c = co_c; sh_cn_c = cn_c; }
    }
    __syncthreads();

    // ---- reduce this batch's 256 block partials (3 KB) ----
    float c1 = ct_p[b * 256 + tid];
    float c2 = co_p[b * 256 + tid];
    unsigned int c3 = cn_p[b * 256 + tid];
    #pragma unroll
    for (int off = 32; off > 0; off >>= 1) {
        c1 += __shfl_down(c1, off);
        c2 += __shfl_down(c2, off);
        c3 += __shfl_down(c3, off);
    }
    __shared__ float r1[4], r2[4];
    __shared__ unsigned int r3[4];
    const int wave = tid >> 6, lane = tid & 63;
    if (lane == 0) { r1[wave] = c1; r2[wave] = c2; r3[wave] = c3; }
    __syncthreads();
    if (tid == 0) {
        S_ct[b] = r1[0] + r1[1] + r1[2] + r1[3] + sh_ct_c;
        S_co[b] = r2[0] + r2[1] + r2[2] + r2[3] + sh_co_c;
        S_cn[b] = r3[0] + r3[1] + r3[2] + r3[3] + sh_cn_c;
    }
}

// K3: one wave, 24 scalar loads -> 3 outputs.
__global__ void finalize_kernel(const float* __restrict__ S_ct,
                                const float* __restrict__ S_co,
                                const unsigned int* __restrict__ S_cn,
                                float* __restrict__ out) {
    const int l = threadIdx.x;
    float ct = 0.0f, co = 0.0f;
    if (l < B) {
        ct = S_ct[l];
        co = S_co[l] / (4.0f * (float)S_cn[l]);
    }
    #pragma unroll
    for (int off = 4; off > 0; off >>= 1) {
        ct += __shfl_down(ct, off);
        co += __shfl_down(co, off);
    }
    if (l == 0) {
        const float cls = ct * (0.01f / 8.0f);
        co *= (1.0f / 8.0f);
        out[0] = cls + co;
        out[1] = cls;
        out[2] = co;
    }
}

extern "C" void kernel_launch(void* const* d_in, const int* in_sizes, int n_in,
                              void* d_out, int out_size, void* d_ws, size_t ws_size,
                              hipStream_t stream) {
    const float* boxes   = (const float*)d_in[0];
    const float* classes = (const float*)d_in[1];
    const float* anchors = (const float*)d_in[2];
    const float* gt      = (const float*)d_in[3];
    const int*   nobj    = (const int*)d_in[4];
    float* out = (float*)d_out;

    unsigned long long* part = (unsigned long long*)((char*)d_ws + WS_PART);
    float* ct_p        = (float*)((char*)d_ws + WS_CT);
    float* co_p        = (float*)((char*)d_ws + WS_CO);
    unsigned int* cn_p = (unsigned int*)((char*)d_ws + WS_CN);
    float* S_ct        = (float*)((char*)d_ws + WS_SCT);
    float* S_co        = (float*)((char*)d_ws + WS_SCO);
    unsigned int* S_cn = (unsigned int*)((char*)d_ws + WS_SCN);

    dim3 grid(A / 256, B);
    fused_kernel<<<grid, 256, 0, stream>>>(boxes, classes, anchors, gt, nobj,
                                           part, ct_p, co_p, cn_p);
    correct_kernel<<<dim3(B), 256, 0, stream>>>(boxes, classes, anchors, gt,
                                                nobj, part, ct_p, co_p, cn_p,
                                                S_ct, S_co, S_cn);
    finalize_kernel<<<1, 64, 0, stream>>>(S_ct, S_co, S_cn, out);
}